// Round 2
// baseline (91.949 us; speedup 1.0000x reference)
//
#include <hip/hip_runtime.h>
#include <math.h>

#define BB 128   // batch
#define VV 4     // views
#define NN 512   // BB*VV rows
#define DD 128   // feature dim
#define NT 256   // threads per block

// ---------------------------------------------------------------------------
// Fused kernel: one block per anchor.
//  Phase 1: all 512 row norms from raw features (redundant per block, but
//           removes a kernel launch + global round-trip; feat is 256 KB and
//           L2-resident, so re-reads are cheap).
//  Phase 2: anchor's distance row d[j] = sqrt(max(sa + sj - 2*dot_n, 0))
//           with dot_n = dot_raw(a,j) * inv_a * inv_j (== reference's
//           normalize-then-dot to ~1e-7).
//  Phase 3: ballot-based compaction into pos/neg distance lists
//           (8 LDS atomics per block instead of 512).
//  Phase 4: div-free pair loop: sum/count of relu(d_ap - d_an) > 0.
//  Writes deterministic per-anchor partials (no zero-init, no global atomics).
// ---------------------------------------------------------------------------
__global__ __launch_bounds__(NT)
void fused_triplet(const float* __restrict__ feat,
                   const int* __restrict__ labels,
                   float* __restrict__ psum,
                   float* __restrict__ pcnt) {
    __shared__ float s_inv[NN];
    __shared__ float s_sn[NN];      // post-normalization sq-norm = ss*inv*inv
    __shared__ float s_anc[DD];     // anchor row pre-scaled by inv_a
    __shared__ float s_d[NN];
    __shared__ float s_pos[NN];
    __shared__ float s_neg[NN];
    __shared__ int   s_lab[BB];
    __shared__ int   s_np, s_nn;
    __shared__ float s_wsum[NT / 64];
    __shared__ unsigned int s_wcnt[NT / 64];

    const int a   = blockIdx.x;
    const int tid = threadIdx.x;

    if (tid < BB) s_lab[tid] = labels[tid];
    if (tid == 0) { s_np = 0; s_nn = 0; }

    // Phase 1: norms of all rows (row r -> feat[b= r%128, v= r/128, :])
    for (int r = tid; r < NN; r += NT) {
        int b = r & (BB - 1), v = r >> 7;
        const float4* row = (const float4*)(feat + (size_t)b * (VV * DD) + v * DD);
        float ss = 0.f;
        #pragma unroll
        for (int k = 0; k < DD / 4; ++k) {
            float4 x = row[k];
            ss = fmaf(x.x, x.x, fmaf(x.y, x.y, fmaf(x.z, x.z, fmaf(x.w, x.w, ss))));
        }
        float inv = 1.f / fmaxf(sqrtf(ss), 1e-12f);
        s_inv[r] = inv;
        s_sn[r]  = ss * inv * inv;
    }
    __syncthreads();

    // anchor row, pre-scaled by its inv-norm (matches reference rounding on
    // the anchor side; j side differs at ~1e-7, far under threshold)
    {
        int b = a & (BB - 1), v = a >> 7;
        const float* arow = feat + (size_t)b * (VV * DD) + v * DD;
        float inva = s_inv[a];
        if (tid < DD) s_anc[tid] = arow[tid] * inva;
    }
    __syncthreads();

    // Phase 2: distance row
    const float sa = s_sn[a];
    for (int j = tid; j < NN; j += NT) {
        int b = j & (BB - 1), v = j >> 7;
        const float4* row = (const float4*)(feat + (size_t)b * (VV * DD) + v * DD);
        const float4* anc = (const float4*)s_anc;
        float dot = 0.f;
        #pragma unroll
        for (int k = 0; k < DD / 4; ++k) {
            float4 r = row[k];
            float4 c = anc[k];
            dot = fmaf(r.x, c.x, fmaf(r.y, c.y, fmaf(r.z, c.z, fmaf(r.w, c.w, dot))));
        }
        dot *= s_inv[j];
        float sq = fmaxf(sa + s_sn[j] - 2.f * dot, 0.f);
        s_d[j] = (sq > 0.f) ? sqrtf(sq) : 0.f;   // safe_sqrt semantics
    }
    __syncthreads();

    // Phase 3: ballot compaction (order within lists is irrelevant to the sum)
    const int la   = s_lab[a & (BB - 1)];
    const int lane = tid & 63;
    for (int j = tid; j < NN; j += NT) {
        bool ispos = (s_lab[j & (BB - 1)] == la) & (j != a);
        bool isneg = (s_lab[j & (BB - 1)] != la);
        unsigned long long mp = __ballot(ispos);
        unsigned long long mn = __ballot(isneg);
        int basep = 0, basen = 0;
        if (lane == 0) {
            basep = atomicAdd(&s_np, (int)__popcll(mp));
            basen = atomicAdd(&s_nn, (int)__popcll(mn));
        }
        basep = __shfl(basep, 0);
        basen = __shfl(basen, 0);
        unsigned long long below = (1ull << lane) - 1ull;
        if (ispos) s_pos[basep + (int)__popcll(mp & below)] = s_d[j];
        if (isneg) s_neg[basen + (int)__popcll(mn & below)] = s_d[j];
    }
    __syncthreads();

    // Phase 4: pair loop, no division
    const int np = s_np, nn = s_nn;
    float lsum = 0.f;
    unsigned int lcnt = 0;
    for (int p = 0; p < np; ++p) {
        float dp = s_pos[p];                 // LDS broadcast
        for (int n = tid; n < nn; n += NT) {
            float diff = dp - s_neg[n];
            if (diff > 0.f) { lsum += diff; lcnt++; }
        }
    }

    // block reduce
    #pragma unroll
    for (int off = 32; off > 0; off >>= 1) {
        lsum += __shfl_down(lsum, off);
        lcnt += __shfl_down(lcnt, off);
    }
    if (lane == 0) { s_wsum[tid >> 6] = lsum; s_wcnt[tid >> 6] = lcnt; }
    __syncthreads();
    if (tid == 0) {
        float S = s_wsum[0] + s_wsum[1] + s_wsum[2] + s_wsum[3];
        unsigned int C = s_wcnt[0] + s_wcnt[1] + s_wcnt[2] + s_wcnt[3];
        psum[a] = S;
        pcnt[a] = (float)C;                  // counts < 2^24: exact in fp32
    }
}

// ---------------------------------------------------------------------------
// Final reduce: 512 partials -> scalar
// ---------------------------------------------------------------------------
__global__ __launch_bounds__(NT)
void reduce_final(const float* __restrict__ psum,
                  const float* __restrict__ pcnt,
                  float* __restrict__ out) {
    int tid = threadIdx.x;
    float s = psum[tid] + psum[tid + NT];
    float c = pcnt[tid] + pcnt[tid + NT];
    #pragma unroll
    for (int off = 32; off > 0; off >>= 1) {
        s += __shfl_down(s, off);
        c += __shfl_down(c, off);
    }
    __shared__ float ws[NT / 64], wc[NT / 64];
    if ((tid & 63) == 0) { ws[tid >> 6] = s; wc[tid >> 6] = c; }
    __syncthreads();
    if (tid == 0) {
        float S = ws[0] + ws[1] + ws[2] + ws[3];
        float C = wc[0] + wc[1] + wc[2] + wc[3];
        out[0] = (C > 0.f) ? S / C : 0.f;
    }
}

extern "C" void kernel_launch(void* const* d_in, const int* in_sizes, int n_in,
                              void* d_out, int out_size, void* d_ws, size_t ws_size,
                              hipStream_t stream) {
    const float* feat   = (const float*)d_in[0];   // [128, 4, 128] fp32
    const int*   labels = (const int*)d_in[1];     // [128] int32
    float* out = (float*)d_out;

    float* psum = (float*)d_ws;          // NN floats
    float* pcnt = psum + NN;             // NN floats

    fused_triplet<<<NN, NT, 0, stream>>>(feat, labels, psum, pcnt);
    reduce_final<<<1, NT, 0, stream>>>(psum, pcnt, out);
}

// Round 3
// 85.300 us; speedup vs baseline: 1.0779x; 1.0779x over previous
//
#include <hip/hip_runtime.h>
#include <math.h>

#define BB 128   // batch
#define VV 4     // views
#define NN 512   // BB*VV rows
#define DD 128   // feature dim

// ---------------------------------------------------------------------------
// K1: L2-normalize each row (one wave per row). emb row i = feat[i%128][i/128].
// Writes normalized emb [NN][DD] and post-normalization sq_norm (matches
// reference's sum(emb*emb) after normalization).
// ---------------------------------------------------------------------------
__global__ __launch_bounds__(64)
void normalize_kernel(const float* __restrict__ feat,
                      float* __restrict__ emb,
                      float* __restrict__ sqn) {
    int i = blockIdx.x;        // row in [0, NN)
    int tid = threadIdx.x;     // 0..63

    int b = i & (BB - 1);
    int v = i >> 7;
    const float* src = feat + (size_t)b * (VV * DD) + (size_t)v * DD;

    float x0 = src[tid];
    float x1 = src[tid + 64];
    float ss = x0 * x0 + x1 * x1;
    #pragma unroll
    for (int off = 32; off > 0; off >>= 1) ss += __shfl_xor(ss, off);

    float inv = 1.f / fmaxf(sqrtf(ss), 1e-12f);
    float y0 = x0 * inv, y1 = x1 * inv;
    emb[i * DD + tid]      = y0;
    emb[i * DD + tid + 64] = y1;

    float s2 = y0 * y0 + y1 * y1;
    #pragma unroll
    for (int off = 32; off > 0; off >>= 1) s2 += __shfl_xor(s2, off);
    if (tid == 0) sqn[i] = s2;
}

// ---------------------------------------------------------------------------
// K2: distance matrix, 16x16 tile per block, grid (32, 32).
// Thread (tx,ty) computes d[a0+ty][j0+tx]. Block working set = 32 rows
// (16 KB) -> L1 resident; 16 lanes share each j-row address (coalesced).
// ---------------------------------------------------------------------------
__global__ __launch_bounds__(256)
void dist_kernel(const float* __restrict__ emb,
                 const float* __restrict__ sqn,
                 float* __restrict__ dmat) {
    int tx = threadIdx.x & 15;
    int ty = threadIdx.x >> 4;
    int a = (blockIdx.y << 4) + ty;
    int j = (blockIdx.x << 4) + tx;

    const float4* arow = (const float4*)(emb + a * DD);
    const float4* jrow = (const float4*)(emb + j * DD);

    float s0 = 0.f, s1 = 0.f, s2 = 0.f, s3 = 0.f;  // 4 independent chains
    #pragma unroll
    for (int k = 0; k < DD / 4; ++k) {
        float4 r = arow[k];
        float4 c = jrow[k];
        s0 = fmaf(r.x, c.x, s0);
        s1 = fmaf(r.y, c.y, s1);
        s2 = fmaf(r.z, c.z, s2);
        s3 = fmaf(r.w, c.w, s3);
    }
    float dot = (s0 + s1) + (s2 + s3);
    float sq = fmaxf(sqn[a] + sqn[j] - 2.f * dot, 0.f);
    dmat[a * NN + j] = (sq > 0.f) ? sqrtf(sq) : 0.f;   // safe_sqrt semantics
}

// ---------------------------------------------------------------------------
// K3: per-anchor triplet reduce. One block per anchor, 256 threads.
// Reads the anchor's distance row (coalesced), ballot-compacts into
// positive/negative lists, pair-loops, writes deterministic partials.
// ---------------------------------------------------------------------------
__global__ __launch_bounds__(256)
void triplet_kernel(const float* __restrict__ dmat,
                    const int* __restrict__ labels,
                    float* __restrict__ psum,
                    float* __restrict__ pcnt) {
    __shared__ float s_pos[NN];
    __shared__ float s_neg[NN];
    __shared__ int   s_lab[BB];
    __shared__ int   s_np, s_nn;
    __shared__ float s_wsum[4];
    __shared__ unsigned int s_wcnt[4];

    const int a   = blockIdx.x;
    const int tid = threadIdx.x;
    const int lane = tid & 63;

    if (tid < BB) s_lab[tid] = labels[tid];
    if (tid == 0) { s_np = 0; s_nn = 0; }

    float d0 = dmat[a * NN + tid];
    float d1 = dmat[a * NN + tid + 256];
    __syncthreads();

    const int la = s_lab[a & (BB - 1)];
    // compaction round 1: j = tid, value d0; round 2: j = tid+256, value d1
    #pragma unroll
    for (int rnd = 0; rnd < 2; ++rnd) {
        int j = tid + (rnd << 8);
        float dj = (rnd == 0) ? d0 : d1;
        bool same = (s_lab[j & (BB - 1)] == la);
        bool ispos = same & (j != a);
        bool isneg = !same;
        unsigned long long mp = __ballot(ispos);
        unsigned long long mn = __ballot(isneg);
        int basep = 0, basen = 0;
        if (lane == 0) {
            basep = atomicAdd(&s_np, (int)__popcll(mp));
            basen = atomicAdd(&s_nn, (int)__popcll(mn));
        }
        basep = __shfl(basep, 0);
        basen = __shfl(basen, 0);
        unsigned long long below = (1ull << lane) - 1ull;
        if (ispos) s_pos[basep + (int)__popcll(mp & below)] = dj;
        if (isneg) s_neg[basen + (int)__popcll(mn & below)] = dj;
    }
    __syncthreads();

    const int np = s_np, nn = s_nn;
    float lsum = 0.f;
    unsigned int lcnt = 0;
    for (int p = 0; p < np; ++p) {
        float dp = s_pos[p];                   // LDS broadcast
        for (int n = tid; n < nn; n += 256) {
            float diff = dp - s_neg[n];
            if (diff > 0.f) { lsum += diff; lcnt++; }
        }
    }

    #pragma unroll
    for (int off = 32; off > 0; off >>= 1) {
        lsum += __shfl_down(lsum, off);
        lcnt += __shfl_down(lcnt, off);
    }
    if (lane == 0) { s_wsum[tid >> 6] = lsum; s_wcnt[tid >> 6] = lcnt; }
    __syncthreads();
    if (tid == 0) {
        psum[a] = s_wsum[0] + s_wsum[1] + s_wsum[2] + s_wsum[3];
        pcnt[a] = (float)(s_wcnt[0] + s_wcnt[1] + s_wcnt[2] + s_wcnt[3]);
    }
}

// ---------------------------------------------------------------------------
// K4: 512 partials -> scalar
// ---------------------------------------------------------------------------
__global__ __launch_bounds__(256)
void reduce_final(const float* __restrict__ psum,
                  const float* __restrict__ pcnt,
                  float* __restrict__ out) {
    int tid = threadIdx.x;
    float s = psum[tid] + psum[tid + 256];
    float c = pcnt[tid] + pcnt[tid + 256];
    #pragma unroll
    for (int off = 32; off > 0; off >>= 1) {
        s += __shfl_down(s, off);
        c += __shfl_down(c, off);
    }
    __shared__ float ws[4], wc[4];
    if ((tid & 63) == 0) { ws[tid >> 6] = s; wc[tid >> 6] = c; }
    __syncthreads();
    if (tid == 0) {
        float S = ws[0] + ws[1] + ws[2] + ws[3];
        float C = wc[0] + wc[1] + wc[2] + wc[3];
        out[0] = (C > 0.f) ? S / C : 0.f;
    }
}

extern "C" void kernel_launch(void* const* d_in, const int* in_sizes, int n_in,
                              void* d_out, int out_size, void* d_ws, size_t ws_size,
                              hipStream_t stream) {
    const float* feat   = (const float*)d_in[0];   // [128, 4, 128] fp32
    const int*   labels = (const int*)d_in[1];     // [128] int32
    float* out = (float*)d_out;

    float* emb  = (float*)d_ws;                  // NN*DD
    float* sqn  = emb + (size_t)NN * DD;         // NN
    float* dmat = sqn + NN;                      // NN*NN
    float* psum = dmat + (size_t)NN * NN;        // NN
    float* pcnt = psum + NN;                     // NN

    normalize_kernel<<<NN, 64, 0, stream>>>(feat, emb, sqn);
    dist_kernel<<<dim3(NN / 16, NN / 16), 256, 0, stream>>>(emb, sqn, dmat);
    triplet_kernel<<<NN, 256, 0, stream>>>(dmat, labels, psum, pcnt);
    reduce_final<<<1, 256, 0, stream>>>(psum, pcnt, out);
}

// Round 4
// 71.397 us; speedup vs baseline: 1.2879x; 1.1947x over previous
//
#include <hip/hip_runtime.h>
#include <math.h>

#define BB 128   // batch
#define VV 4     // views
#define NN 512   // BB*VV rows
#define DD 128   // feature dim
#define NT 256   // threads per block

// ---------------------------------------------------------------------------
// One block per anchor. Single fused read pass over all 512 rows computes
// BOTH ss_j = <row_j, row_j> and dot_j = <row_j, anchor> (8 lanes per row,
// 4 float4 loads/lane, 3-step butterfly reduce -> coalesced, 4 KB live set
// per wave, everything L1/L2-resident). Then:
//   d_j = sqrt(max(sn_a + sn_j - 2*dot_j*inv_a*inv_j, 0))   (== reference's
//   normalize-then-dot to ~1e-7; round-2 verified absmax 0.0 with this form)
// followed by ballot compaction into pos/neg lists and the relu pair loop.
// Writes deterministic per-anchor partials (no init, no global atomics).
// ---------------------------------------------------------------------------
__global__ __launch_bounds__(NT)
void fused_triplet(const float* __restrict__ feat,
                   const int* __restrict__ labels,
                   float* __restrict__ psum,
                   float* __restrict__ pcnt) {
    __shared__ float s_ss[NN];
    __shared__ float s_dot[NN];
    __shared__ float s_pos[NN];
    __shared__ float s_neg[NN];
    __shared__ int   s_lab[BB];
    __shared__ int   s_np, s_nn;
    __shared__ float s_wsum[NT / 64];
    __shared__ unsigned int s_wcnt[NT / 64];

    const int a    = blockIdx.x;
    const int tid  = threadIdx.x;
    const int wave = tid >> 6;      // 0..3
    const int lane = tid & 63;
    const int grp  = lane >> 3;     // 8 groups of 8 lanes
    const int l8   = lane & 7;

    if (tid < BB) s_lab[tid] = labels[tid];
    if (tid == 0) { s_np = 0; s_nn = 0; }

    // anchor row fragments: this lane's 4 float4s (positions l8, l8+8, ...)
    const int ab = a & (BB - 1), av = a >> 7;
    const float4* arow = (const float4*)(feat + (size_t)ab * (VV * DD) + av * DD);
    float4 af0 = arow[l8];
    float4 af1 = arow[l8 + 8];
    float4 af2 = arow[l8 + 16];
    float4 af3 = arow[l8 + 24];

    // fused ss + dot pass: wave w covers rows [w*128, w*128+128), 8 rows/iter
    #pragma unroll 4
    for (int it = 0; it < 16; ++it) {
        const int j  = (wave << 7) + (it << 3) + grp;
        const int jb = j & (BB - 1), jv = j >> 7;
        const float4* jrow = (const float4*)(feat + (size_t)jb * (VV * DD) + jv * DD);
        float4 x0 = jrow[l8];
        float4 x1 = jrow[l8 + 8];
        float4 x2 = jrow[l8 + 16];
        float4 x3 = jrow[l8 + 24];

        float ss = 0.f, dt = 0.f;
        ss = fmaf(x0.x, x0.x, fmaf(x0.y, x0.y, fmaf(x0.z, x0.z, fmaf(x0.w, x0.w, ss))));
        ss = fmaf(x1.x, x1.x, fmaf(x1.y, x1.y, fmaf(x1.z, x1.z, fmaf(x1.w, x1.w, ss))));
        ss = fmaf(x2.x, x2.x, fmaf(x2.y, x2.y, fmaf(x2.z, x2.z, fmaf(x2.w, x2.w, ss))));
        ss = fmaf(x3.x, x3.x, fmaf(x3.y, x3.y, fmaf(x3.z, x3.z, fmaf(x3.w, x3.w, ss))));
        dt = fmaf(x0.x, af0.x, fmaf(x0.y, af0.y, fmaf(x0.z, af0.z, fmaf(x0.w, af0.w, dt))));
        dt = fmaf(x1.x, af1.x, fmaf(x1.y, af1.y, fmaf(x1.z, af1.z, fmaf(x1.w, af1.w, dt))));
        dt = fmaf(x2.x, af2.x, fmaf(x2.y, af2.y, fmaf(x2.z, af2.z, fmaf(x2.w, af2.w, dt))));
        dt = fmaf(x3.x, af3.x, fmaf(x3.y, af3.y, fmaf(x3.z, af3.z, fmaf(x3.w, af3.w, dt))));

        // butterfly reduce across the 8 lanes of this row group
        #pragma unroll
        for (int off = 4; off > 0; off >>= 1) {
            ss += __shfl_xor(ss, off);
            dt += __shfl_xor(dt, off);
        }
        if (l8 == 0) { s_ss[j] = ss; s_dot[j] = dt; }
    }
    __syncthreads();

    // distances for j = tid, tid+256
    const float ssa  = s_ss[a];
    const float inva = 1.f / fmaxf(sqrtf(ssa), 1e-12f);
    const float sna  = ssa * inva * inva;
    float dreg[2];
    #pragma unroll
    for (int rnd = 0; rnd < 2; ++rnd) {
        const int j = tid + (rnd << 8);
        float ssj  = s_ss[j];
        float invj = 1.f / fmaxf(sqrtf(ssj), 1e-12f);
        float snj  = ssj * invj * invj;
        float dot  = s_dot[j] * inva * invj;
        float sq   = fmaxf(sna + snj - 2.f * dot, 0.f);
        dreg[rnd]  = (sq > 0.f) ? sqrtf(sq) : 0.f;   // safe_sqrt semantics
    }

    // ballot compaction into pos/neg lists (8 LDS atomics per block)
    const int la = s_lab[a & (BB - 1)];
    #pragma unroll
    for (int rnd = 0; rnd < 2; ++rnd) {
        const int j = tid + (rnd << 8);
        bool same  = (s_lab[j & (BB - 1)] == la);
        bool ispos = same & (j != a);
        bool isneg = !same;
        unsigned long long mp = __ballot(ispos);
        unsigned long long mn = __ballot(isneg);
        int basep = 0, basen = 0;
        if (lane == 0) {
            basep = atomicAdd(&s_np, (int)__popcll(mp));
            basen = atomicAdd(&s_nn, (int)__popcll(mn));
        }
        basep = __shfl(basep, 0);
        basen = __shfl(basen, 0);
        unsigned long long below = (1ull << lane) - 1ull;
        if (ispos) s_pos[basep + (int)__popcll(mp & below)] = dreg[rnd];
        if (isneg) s_neg[basen + (int)__popcll(mn & below)] = dreg[rnd];
    }
    __syncthreads();

    // pair loop: sum/count of relu(d_ap - d_an) > 0
    const int np = s_np, nn = s_nn;
    float lsum = 0.f;
    unsigned int lcnt = 0;
    for (int p = 0; p < np; ++p) {
        float dp = s_pos[p];                   // LDS broadcast
        for (int n = tid; n < nn; n += NT) {
            float diff = dp - s_neg[n];
            if (diff > 0.f) { lsum += diff; lcnt++; }
        }
    }

    #pragma unroll
    for (int off = 32; off > 0; off >>= 1) {
        lsum += __shfl_down(lsum, off);
        lcnt += __shfl_down(lcnt, off);
    }
    if (lane == 0) { s_wsum[wave] = lsum; s_wcnt[wave] = lcnt; }
    __syncthreads();
    if (tid == 0) {
        psum[a] = s_wsum[0] + s_wsum[1] + s_wsum[2] + s_wsum[3];
        pcnt[a] = (float)(s_wcnt[0] + s_wcnt[1] + s_wcnt[2] + s_wcnt[3]);
    }
}

// ---------------------------------------------------------------------------
// Final reduce: 512 partials -> scalar
// ---------------------------------------------------------------------------
__global__ __launch_bounds__(NT)
void reduce_final(const float* __restrict__ psum,
                  const float* __restrict__ pcnt,
                  float* __restrict__ out) {
    int tid = threadIdx.x;
    float s = psum[tid] + psum[tid + NT];
    float c = pcnt[tid] + pcnt[tid + NT];
    #pragma unroll
    for (int off = 32; off > 0; off >>= 1) {
        s += __shfl_down(s, off);
        c += __shfl_down(c, off);
    }
    __shared__ float ws[NT / 64], wc[NT / 64];
    if ((tid & 63) == 0) { ws[tid >> 6] = s; wc[tid >> 6] = c; }
    __syncthreads();
    if (tid == 0) {
        float S = ws[0] + ws[1] + ws[2] + ws[3];
        float C = wc[0] + wc[1] + wc[2] + wc[3];
        out[0] = (C > 0.f) ? S / C : 0.f;
    }
}

extern "C" void kernel_launch(void* const* d_in, const int* in_sizes, int n_in,
                              void* d_out, int out_size, void* d_ws, size_t ws_size,
                              hipStream_t stream) {
    const float* feat   = (const float*)d_in[0];   // [128, 4, 128] fp32
    const int*   labels = (const int*)d_in[1];     // [128] int32
    float* out = (float*)d_out;

    float* psum = (float*)d_ws;          // NN floats
    float* pcnt = psum + NN;             // NN floats

    fused_triplet<<<NN, NT, 0, stream>>>(feat, labels, psum, pcnt);
    reduce_final<<<1, NT, 0, stream>>>(psum, pcnt, out);
}